// Round 17
// baseline (432.797 us; speedup 1.0000x reference)
//
#include <hip/hip_runtime.h>

// GraphSAGE (2x SAGEConv mean + global_mean_pool) on MI355X.
// R17: harvest the tail. (1) t2 path: mgemm12 cols>=64 atomicAdd directly
// into pool (+b2) - o128 buffer deleted (-25.6MB RW + pool2 kernel);
// (2) agg2q atomicAdds its means into pool - agg2h deleted (-25.6MB RW);
// (3) pscan inlined into bbuild as a 512-thread LDS scan; (4) gcnt folded
// into x2hw; (5) part widened to 8192 edges/block (less write-allocate amp,
// half the reserve atomics). 10 -> 8 dispatches.

constexpr int NN = 100000;    // nodes
constexpr int NE = 3200000;   // edges
constexpr int C1 = 128;       // IN_C == HID_C
constexpr int C2 = 64;        // OUT_C
constexpr int NG = 1024;      // graphs

constexpr int NBK = (NN + 511) >> 9;   // 196 buckets of 512 nodes
constexpr int CAP = 18176;             // padded edges per bucket (mean 16327)
constexpr int NSH = 13;                // src shards (harmless, 1-pass)

typedef unsigned int u32;
typedef unsigned short u16;
typedef unsigned char u8;
typedef _Float16 f16;
typedef f16 f16x8 __attribute__((ext_vector_type(8)));
typedef float f32x4 __attribute__((ext_vector_type(4)));

__device__ __forceinline__ float h2f(u32 bits16) {
  f16 h; u16 b = (u16)bits16;
  __builtin_memcpy(&h, &b, 2);
  return (float)h;
}
__device__ __forceinline__ u16 f2h(float f) {
  f16 h = (f16)f; u16 b;
  __builtin_memcpy(&b, &h, 2);
  return b;
}
__device__ __forceinline__ u32 packh2(float a, float b) {
  return (u32)f2h(a) | ((u32)f2h(b) << 16);
}
// pack 4 floats -> 4 fp8 e4m3 (one u32)
__device__ __forceinline__ u32 packq4(float a, float b, float c, float d) {
  int q = 0;
  q = __builtin_amdgcn_cvt_pk_fp8_f32(a, b, q, false);
  q = __builtin_amdgcn_cvt_pk_fp8_f32(c, d, q, true);
  return (u32)q;
}
// accumulate 4 fp8 (one u32) into 4 fp32
__device__ __forceinline__ void acc4(u32 g, float& a0, float& a1,
                                     float& a2, float& a3) {
  const auto p = __builtin_amdgcn_cvt_pk_f32_fp8((int)g, false);
  const auto q = __builtin_amdgcn_cvt_pk_f32_fp8((int)g, true);
  a0 += p[0]; a1 += p[1]; a2 += q[0]; a3 += q[1];
}
// 8 fp8 (uint2) -> 8 fp16 (uint4)
__device__ __forceinline__ uint4 q8toh8(uint2 g) {
  const auto p0 = __builtin_amdgcn_cvt_pk_f32_fp8((int)g.x, false);
  const auto p1 = __builtin_amdgcn_cvt_pk_f32_fp8((int)g.x, true);
  const auto p2 = __builtin_amdgcn_cvt_pk_f32_fp8((int)g.y, false);
  const auto p3 = __builtin_amdgcn_cvt_pk_f32_fp8((int)g.y, true);
  uint4 o;
  o.x = packh2(p0[0], p0[1]);
  o.y = packh2(p1[0], p1[1]);
  o.z = packh2(p2[0], p2[1]);
  o.w = packh2(p3[0], p3[1]);
  return o;
}

// ------- fused prep: x -> fp16+fp8, weights -> fp16 [N][K], gcur init,
//         gcnt (graph node counts) -------
__global__ __launch_bounds__(256)
void sage_x2hw(const float* __restrict__ x, u16* __restrict__ xh,
               u32* __restrict__ xq,
               const float* __restrict__ W1l, const float* __restrict__ W1r,
               const float* __restrict__ W2l, const float* __restrict__ W2r,
               u16* __restrict__ wt1, u16* __restrict__ wt2,
               int* __restrict__ gcur,
               const int* __restrict__ batch, int* __restrict__ gcnt) {
  const int id = blockIdx.x * 256 + threadIdx.x;
  constexpr int NX = NN * 32;
  constexpr int W1E = NX + 128 * 256;
  constexpr int W2E = W1E + 128 * 128;
  constexpr int GCE = W2E + NBK;
  if (id < NX) {
    const float4 v = ((const float4*)x)[id];
    uint2 o;
    o.x = packh2(v.x, v.y);
    o.y = packh2(v.z, v.w);
    ((uint2*)xh)[id] = o;
    xq[id] = packq4(v.x, v.y, v.z, v.w);
  } else if (id < W1E) {
    const int id2 = id - NX;
    const int n = id2 >> 8, k = id2 & 255;
    const float v = (k < 128) ? W1l[k * 128 + n] : W1r[(k - 128) * 128 + n];
    wt1[id2] = f2h(v);
  } else if (id < W2E) {
    const int id3 = id - W1E;
    const int n = id3 >> 7, k = id3 & 127;
    const float v = (n < 64) ? W2l[k * 64 + n] : W2r[k * 64 + (n - 64)];
    wt2[id3] = f2h(v);
  } else if (id < GCE) {
    const int b = id - W2E;
    gcur[b] = b * CAP;
  } else if (id < GCE + NN) {
    atomicAdd(&gcnt[batch[id - GCE]], 1);
  }
}

// ------- partition edges into padded per-bucket regions of gpart -------
// 8192 edges/block, single edge read cached in registers.
__global__ __launch_bounds__(256)
void sage_part(const int* __restrict__ esrc, const int* __restrict__ edst,
               int* __restrict__ gcur, u32* __restrict__ gpart) {
  __shared__ int h[NBK], cur[NBK];
  for (int i = threadIdx.x; i < NBK; i += 256) h[i] = 0;
  __syncthreads();
  const int e0 = blockIdx.x * 8192 + threadIdx.x * 4;
  int4 dv[8], sv[8];
  bool val[8];
#pragma unroll
  for (int j = 0; j < 8; ++j) {
    const int e = e0 + j * 1024;
    val[j] = (e < NE);
    if (val[j]) {
      dv[j] = *(const int4*)(edst + e);
      sv[j] = *(const int4*)(esrc + e);
    }
  }
#pragma unroll
  for (int j = 0; j < 8; ++j) {
    if (val[j]) {
      atomicAdd(&h[dv[j].x >> 9], 1);
      atomicAdd(&h[dv[j].y >> 9], 1);
      atomicAdd(&h[dv[j].z >> 9], 1);
      atomicAdd(&h[dv[j].w >> 9], 1);
    }
  }
  __syncthreads();
  for (int i = threadIdx.x; i < NBK; i += 256)
    cur[i] = h[i] ? atomicAdd(&gcur[i], h[i]) : 0;
  __syncthreads();
#pragma unroll
  for (int j = 0; j < 8; ++j) {
    if (val[j]) {
      int bk, p;
      bk = dv[j].x >> 9; p = atomicAdd(&cur[bk], 1);
      if (p < (bk + 1) * CAP) gpart[p] = ((u32)sv[j].x << 9) | (u32)(dv[j].x & 511);
      bk = dv[j].y >> 9; p = atomicAdd(&cur[bk], 1);
      if (p < (bk + 1) * CAP) gpart[p] = ((u32)sv[j].y << 9) | (u32)(dv[j].y & 511);
      bk = dv[j].z >> 9; p = atomicAdd(&cur[bk], 1);
      if (p < (bk + 1) * CAP) gpart[p] = ((u32)sv[j].z << 9) | (u32)(dv[j].z & 511);
      bk = dv[j].w >> 9; p = atomicAdd(&cur[bk], 1);
      if (p < (bk + 1) * CAP) gpart[p] = ((u32)sv[j].w << 9) | (u32)(dv[j].w & 511);
    }
  }
}

// ------- one block per bucket: padded gpart -> compact csr + offs -------
// Inlined bucket prefix-scan (replaces pscan kernel), then 2D LDS histogram
// cnt2[node][shard] -> single shard-ordered scatter pass.
__global__ __launch_bounds__(512)
void sage_bbuild(const int* __restrict__ gcur, const u32* __restrict__ gpart,
                 int* __restrict__ offs, int* __restrict__ csr) {
  __shared__ int cnt2[512 * NSH];                     // 26 KB
  __shared__ int ssc[512];
  __shared__ int sh_c0, sh_cnt;
  const int b = blockIdx.x, t = threadIdx.x;
  // bucket prefix over gcur (all blocks do this concurrently)
  int cval = 0;
  if (t < NBK) {
    cval = gcur[t] - t * CAP;
    cval = (cval > CAP) ? CAP : cval;
  }
  ssc[t] = cval;
  __syncthreads();
  for (int d = 1; d < 512; d <<= 1) {
    const int a = (t >= d) ? ssc[t - d] : 0;
    __syncthreads();
    ssc[t] += a;
    __syncthreads();
  }
  if (t == b) { sh_c0 = ssc[t] - cval; sh_cnt = cval; }
  if (b == 0 && t == NBK - 1) offs[NN] = ssc[t];
  __syncthreads();
  const int c0 = sh_c0, cnt = sh_cnt;
  const u32* gp = gpart + (size_t)b * CAP;
  for (int i = t; i < 512 * NSH; i += 512) cnt2[i] = 0;
  __syncthreads();
  for (int e = t; e < cnt; e += 512) {
    const u32 pk = gp[e];
    atomicAdd(&cnt2[(pk & 511) * NSH + (pk >> 22)], 1);
  }
  __syncthreads();
  int deg = 0;
#pragma unroll
  for (int s = 0; s < NSH; ++s) deg += cnt2[t * NSH + s];
  ssc[t] = deg;
  __syncthreads();
  for (int d = 1; d < 512; d <<= 1) {
    const int a = (t >= d) ? ssc[t - d] : 0;
    __syncthreads();
    ssc[t] += a;
    __syncthreads();
  }
  const int pre = ssc[t] - deg;
  const int node = b * 512 + t;
  if (node < NN) offs[node] = c0 + pre;
  int run = c0 + pre;                                 // in-place count->cursor
#pragma unroll
  for (int s = 0; s < NSH; ++s) {
    const int c = cnt2[t * NSH + s];
    cnt2[t * NSH + s] = run;
    run += c;
  }
  __syncthreads();
  for (int e = t; e < cnt; e += 512) {
    const u32 pk = gp[e];
    const int p = atomicAdd(&cnt2[(pk & 511) * NSH + (pk >> 22)], 1);
    csr[p] = (int)(pk >> 9);
  }
}

// ------- aggregation 1: mean of xq (fp8 [NN][128]) -> fp8 out -------
// wave per node; half-wave (32 lanes x u32) covers the 128B row, halves
// interleave edges; 8 gathers in flight per lane.
__global__ __launch_bounds__(256)
void sage_agg1q(const int* __restrict__ offs, const int* __restrict__ csr,
                const u32* __restrict__ xq, u32* __restrict__ agg1) {
  const int node = blockIdx.x * 4 + (threadIdx.x >> 6);
  const int lane = threadIdx.x & 63;
  if (node >= NN) return;
  const int beg = offs[node], end = offs[node + 1];
  const int hf = lane >> 5, l = lane & 31;
  const u32* xb = xq + l;                             // row stride 32 u32
  float a0 = 0, a1 = 0, a2 = 0, a3 = 0;
  int e = beg + hf;
  for (; e + 14 < end; e += 16) {                     // 8 edges/half in flight
    const int i0 = csr[e],      i1 = csr[e + 2],  i2 = csr[e + 4],
              i3 = csr[e + 6],  i4 = csr[e + 8],  i5 = csr[e + 10],
              i6 = csr[e + 12], i7 = csr[e + 14];
    const u32 g0 = xb[(size_t)i0 * 32], g1 = xb[(size_t)i1 * 32],
              g2 = xb[(size_t)i2 * 32], g3 = xb[(size_t)i3 * 32],
              g4 = xb[(size_t)i4 * 32], g5 = xb[(size_t)i5 * 32],
              g6 = xb[(size_t)i6 * 32], g7 = xb[(size_t)i7 * 32];
    acc4(g0, a0, a1, a2, a3); acc4(g1, a0, a1, a2, a3);
    acc4(g2, a0, a1, a2, a3); acc4(g3, a0, a1, a2, a3);
    acc4(g4, a0, a1, a2, a3); acc4(g5, a0, a1, a2, a3);
    acc4(g6, a0, a1, a2, a3); acc4(g7, a0, a1, a2, a3);
  }
  for (; e < end; e += 2)
    acc4(xb[(size_t)csr[e] * 32], a0, a1, a2, a3);
  a0 += __shfl_xor(a0, 32);
  a1 += __shfl_xor(a1, 32);
  a2 += __shfl_xor(a2, 32);
  a3 += __shfl_xor(a3, 32);
  if (hf == 0) {
    const float inv = 1.0f / fmaxf((float)(end - beg), 1.0f);
    agg1[(size_t)node * 32 + l] = packq4(a0 * inv, a1 * inv, a2 * inv, a3 * inv);
  }
}

// ------- aggregation 2 + pool: mean of tq (fp8 [NN][64]) -> pool atomics ----
// wave per node; quarter-wave (16 lanes x u32), 8 gathers in flight; lane<16
// atomicAdds its 4 channel-means into pool[batch[node]] (t2+b2 added by
// mgemm12's epilogue, so pool accumulates the full per-node value).
__global__ __launch_bounds__(256)
void sage_agg2q(const int* __restrict__ offs, const int* __restrict__ csr,
                const u32* __restrict__ tq, const int* __restrict__ batch,
                float* __restrict__ pool) {
  const int node = blockIdx.x * 4 + (threadIdx.x >> 6);
  const int lane = threadIdx.x & 63;
  if (node >= NN) return;
  const int beg = offs[node], end = offs[node + 1];
  const int grp = lane >> 4, l = lane & 15;
  const u32* tb = tq + l;                             // row stride 16 u32
  float a0 = 0, a1 = 0, a2 = 0, a3 = 0;
  int e = beg + grp;
  for (; e + 28 < end; e += 32) {                     // 8 edges/group in flight
    const int i0 = csr[e],      i1 = csr[e + 4],  i2 = csr[e + 8],
              i3 = csr[e + 12], i4 = csr[e + 16], i5 = csr[e + 20],
              i6 = csr[e + 24], i7 = csr[e + 28];
    const u32 g0 = tb[(size_t)i0 * 16], g1 = tb[(size_t)i1 * 16],
              g2 = tb[(size_t)i2 * 16], g3 = tb[(size_t)i3 * 16],
              g4 = tb[(size_t)i4 * 16], g5 = tb[(size_t)i5 * 16],
              g6 = tb[(size_t)i6 * 16], g7 = tb[(size_t)i7 * 16];
    acc4(g0, a0, a1, a2, a3); acc4(g1, a0, a1, a2, a3);
    acc4(g2, a0, a1, a2, a3); acc4(g3, a0, a1, a2, a3);
    acc4(g4, a0, a1, a2, a3); acc4(g5, a0, a1, a2, a3);
    acc4(g6, a0, a1, a2, a3); acc4(g7, a0, a1, a2, a3);
  }
  for (; e < end; e += 4)
    acc4(tb[(size_t)csr[e] * 16], a0, a1, a2, a3);
  a0 += __shfl_xor(a0, 16); a0 += __shfl_xor(a0, 32);
  a1 += __shfl_xor(a1, 16); a1 += __shfl_xor(a1, 32);
  a2 += __shfl_xor(a2, 16); a2 += __shfl_xor(a2, 32);
  a3 += __shfl_xor(a3, 16); a3 += __shfl_xor(a3, 32);
  if (lane < 16) {
    const float inv = 1.0f / fmaxf((float)(end - beg), 1.0f);
    float* pp = pool + (size_t)batch[node] * C2 + l * 4;
    atomicAdd(pp + 0, a0 * inv);
    atomicAdd(pp + 1, a1 * inv);
    atomicAdd(pp + 2, a2 * inv);
    atomicAdd(pp + 3, a3 * inv);
  }
}

// ------- fused MFMA GEMM, B-in-registers mapping -------
// Block 256 (4 waves), 64 rows. Wave w computes col-groups {2w, 2w+1} over
// ALL 64 rows; B-fragments preloaded in registers so MFMA depends only on
// LDS reads (R16: MfmaUtil fix). h = relu([agg1|x]@[W1l;W1r]+b1) in As[0].
// Outputs: cols<64 (t) -> tqb fp8; cols>=64 (t2) -> pool atomics (+b2).
__global__ __launch_bounds__(256)
void sage_mgemm12(const u32* __restrict__ A1q, const u16* __restrict__ A2,
                  const u16* __restrict__ wt1, const u16* __restrict__ wt2,
                  const float* __restrict__ bias, const float* __restrict__ b2,
                  const int* __restrict__ batch,
                  float* __restrict__ pool, u8* __restrict__ tqb) {
  __shared__ __align__(16) u16 As[2][64][128];        // 32 KB
  const int t = threadIdx.x;
  const int r0 = blockIdx.x * 64;
  const int w = t >> 6, l = t & 63;
  const int lr = l & 15, lk = l >> 4;

  // preload GEMM1 B-fragments: c = 2w+j, kt = 0..7  (64 VGPR)
  f16x8 B1[2][8];
#pragma unroll
  for (int j = 0; j < 2; ++j)
#pragma unroll
    for (int kt = 0; kt < 8; ++kt)
      B1[j][kt] = *(const f16x8*)(wt1 + (((2 * w + j) * 16 + lr) * 256 + kt * 32 + lk * 8));

  // stage A1 (fp8 [NN][32 u32] -> f16) into As[0]
#pragma unroll
  for (int i = 0; i < 4; ++i) {
    const int id = i * 256 + t;
    const int row = id >> 4, c = id & 15;
    int gr = r0 + row; gr = (gr < NN) ? gr : NN - 1;
    const uint2 g = *(const uint2*)(A1q + (size_t)gr * 32 + c * 2);
    *(uint4*)(&As[0][row][(c ^ (row & 7)) * 8]) = q8toh8(g);
  }
  // stage A2 (xh fp16) into As[1]
#pragma unroll
  for (int i = 0; i < 4; ++i) {
    const int id = i * 256 + t;
    const int row = id >> 4, c = id & 15;
    int gr = r0 + row; gr = (gr < NN) ? gr : NN - 1;
    const uint4 v = *(const uint4*)(A2 + (size_t)gr * 128 + c * 8);
    *(uint4*)(&As[1][row][(c ^ (row & 7)) * 8]) = v;
  }
  __syncthreads();

  // GEMM1: K = 256 (buf 0: agg1 x W1l, buf 1: xh x W1r)
  f32x4 acc[4][2];
#pragma unroll
  for (int rt = 0; rt < 4; ++rt)
#pragma unroll
    for (int j = 0; j < 2; ++j) acc[rt][j] = (f32x4){0.f, 0.f, 0.f, 0.f};
#pragma unroll
  for (int rt = 0; rt < 4; ++rt) {
    const int ra = rt * 16 + lr;
#pragma unroll
    for (int kt = 0; kt < 8; ++kt) {
      const int buf = kt >> 2, kk = kt & 3;
      const f16x8 a = *(const f16x8*)(&As[buf][ra][((kk * 4 + lk) ^ (ra & 7)) * 8]);
      acc[rt][0] = __builtin_amdgcn_mfma_f32_16x16x32_f16(a, B1[0][kt], acc[rt][0], 0, 0, 0);
      acc[rt][1] = __builtin_amdgcn_mfma_f32_16x16x32_f16(a, B1[1][kt], acc[rt][1], 0, 0, 0);
    }
  }

  // preload GEMM2 B-fragments now (latency hides under h-write + barrier)
  f16x8 B2[2][4];
#pragma unroll
  for (int j = 0; j < 2; ++j)
#pragma unroll
    for (int kt = 0; kt < 4; ++kt)
      B2[j][kt] = *(const f16x8*)(wt2 + (((2 * w + j) * 16 + lr) * 128 + kt * 32 + lk * 8));

  __syncthreads();                                    // all GEMM1 LDS reads done

  // h = relu(acc + b1) -> As[0]; wave w writes cols 32w..32w+31, rows 0..63
#pragma unroll
  for (int j = 0; j < 2; ++j) {
    const int col = (2 * w + j) * 16 + lr;
    const float bv = bias[col];
    const int chb = col >> 3, within = col & 7;
#pragma unroll
    for (int rt = 0; rt < 4; ++rt)
#pragma unroll
      for (int r = 0; r < 4; ++r) {
        const int row = rt * 16 + lk * 4 + r;
        As[0][row][((chb ^ (row & 7)) << 3) + within] =
            f2h(fmaxf(acc[rt][j][r] + bv, 0.f));
      }
  }
  __syncthreads();

  // GEMM2: K = 128, A = h (As[0])
  f32x4 acc2[4][2];
#pragma unroll
  for (int rt = 0; rt < 4; ++rt)
#pragma unroll
    for (int j = 0; j < 2; ++j) acc2[rt][j] = (f32x4){0.f, 0.f, 0.f, 0.f};
#pragma unroll
  for (int rt = 0; rt < 4; ++rt) {
    const int ra = rt * 16 + lr;
#pragma unroll
    for (int kt = 0; kt < 4; ++kt) {
      const f16x8 a = *(const f16x8*)(&As[0][ra][((kt * 4 + lk) ^ (ra & 7)) * 8]);
      acc2[rt][0] = __builtin_amdgcn_mfma_f32_16x16x32_f16(a, B2[0][kt], acc2[rt][0], 0, 0, 0);
      acc2[rt][1] = __builtin_amdgcn_mfma_f32_16x16x32_f16(a, B2[1][kt], acc2[rt][1], 0, 0, 0);
    }
  }
  // outputs: col-group (2w+j) < 4 -> t (fp8); else t2 + b2 -> pool atomics
#pragma unroll
  for (int j = 0; j < 2; ++j) {
    const int col = (2 * w + j) * 16 + lr;
    if (col < 64) {                                   // wave-uniform branch
#pragma unroll
      for (int rt = 0; rt < 4; ++rt)
#pragma unroll
        for (int r = 0; r < 4; ++r) {
          const int row = r0 + rt * 16 + lk * 4 + r;
          if (row < NN) {
            const int pk = __builtin_amdgcn_cvt_pk_fp8_f32(acc2[rt][j][r], acc2[rt][j][r], 0, false);
            tqb[(size_t)row * 64 + col] = (u8)pk;
          }
        }
    } else {
      const int pc = col - 64;
      const float bv = b2[pc];
#pragma unroll
      for (int rt = 0; rt < 4; ++rt)
#pragma unroll
        for (int r = 0; r < 4; ++r) {
          const int row = r0 + rt * 16 + lk * 4 + r;
          if (row < NN)
            atomicAdd(&pool[(size_t)batch[row] * C2 + pc], acc2[rt][j][r] + bv);
        }
    }
  }
}

// ------------- final divide -------------
__global__ __launch_bounds__(256)
void sage_out(const float* __restrict__ pool, const int* __restrict__ gcnt,
              float* __restrict__ out) {
  const int i = blockIdx.x * 256 + threadIdx.x;
  if (i >= NG * C2) return;
  out[i] = pool[i] / fmaxf((float)gcnt[i >> 6], 1.0f);
}

extern "C" void kernel_launch(void* const* d_in, const int* in_sizes, int n_in,
                              void* d_out, int out_size, void* d_ws, size_t ws_size,
                              hipStream_t stream) {
  (void)in_sizes; (void)n_in; (void)out_size; (void)ws_size;
  const float* x     = (const float*)d_in[0];
  const float* W1l   = (const float*)d_in[1];
  const float* b1    = (const float*)d_in[2];
  const float* W1r   = (const float*)d_in[3];
  const float* W2l   = (const float*)d_in[4];
  const float* b2    = (const float*)d_in[5];
  const float* W2r   = (const float*)d_in[6];
  const int*   ei    = (const int*)d_in[7];   // [2, NE]: row0 = src, row1 = dst
  const int*   batch = (const int*)d_in[8];
  const int* esrc = ei;
  const int* edst = ei + NE;
  float* out = (float*)d_out;

  // ---- workspace carve-out (~92 MB) ----
  char* base = (char*)d_ws;
  size_t off = 0;
  auto take = [&](size_t bytes) -> char* {
    char* p = base + off;
    off += (bytes + 255) & ~(size_t)255;
    return p;
  };
  int* gcur     = (int*)take((size_t)NBK * 4);
  int* offs     = (int*)take((size_t)(NN + 1) * 4);
  int* csr      = (int*)take((size_t)NE * 4);
  char* bufA    = take((size_t)NN * 256);   // xh (f16 NNx128)
  char* bufB    = take((size_t)NN * 256);   // agg1 fp8 (12.8M) | tqb @+12.8M
  char* bufC    = take((size_t)NBK * CAP * 4 + (size_t)NN * 128);
                                            // [gpart padded 14.25M | xq 12.8M]
  float* pool   = (float*)take((size_t)NG * C2 * 4);  // \ one contiguous
  int*  gcnt    = (int*)take((size_t)NG * 4);         // / memset region
  u16*  wt1     = (u16*)take((size_t)128 * 256 * 2);
  u16*  wt2     = (u16*)take((size_t)128 * 128 * 2);

  u16*   xh    = (u16*)bufA;
  u32*   agg1  = (u32*)bufB;                // fp8 [NN][32 u32]
  u8*    tqb   = (u8*)(bufB + (size_t)NN * 128);  // fp8 t, behind agg1
  u32*   gpart = (u32*)bufC;                // padded; dead after bbuild
  u32*   xq    = (u32*)(bufC + (size_t)NBK * CAP * 4);  // fp8 x; dead after agg1q

  const size_t zbytes = (size_t)((char*)gcnt + (size_t)NG * 4 - (char*)pool);
  hipMemsetAsync(pool, 0, zbytes, stream);  // pool + gcnt

  sage_x2hw<<<(NN * 32 + 128 * 256 + 128 * 128 + NBK + NN + 255) / 256, 256, 0,
              stream>>>(x, xh, xq, W1l, W1r, W2l, W2r, wt1, wt2, gcur,
                        batch, gcnt);

  // CSR build (part 8192 edges/block; bbuild inlines the bucket scan)
  const int PB = (NE + 8191) / 8192;        // 391 partition blocks
  sage_part<<<PB, 256, 0, stream>>>(esrc, edst, gcur, gpart);
  sage_bbuild<<<NBK, 512, 0, stream>>>(gcur, gpart, offs, csr);

  // layer 1 aggregation (fp8 out)
  sage_agg1q<<<(NN + 3) / 4, 256, 0, stream>>>(offs, csr, xq, agg1);

  // fused GEMMs: t -> tqb fp8; t2 + b2 -> pool atomics
  sage_mgemm12<<<(NN + 63) / 64, 256, 0, stream>>>(agg1, xh, wt1, wt2, b1, b2,
                                                   batch, pool, tqb);

  // layer 2 aggregation + pool (atomics)
  sage_agg2q<<<(NN + 3) / 4, 256, 0, stream>>>(offs, csr, (const u32*)tqb,
                                               batch, pool);

  // final divide
  sage_out<<<(NG * C2 + 255) / 256, 256, 0, stream>>>(pool, gcnt, out);
}

// Round 18
// 273.298 us; speedup vs baseline: 1.5836x; 1.5836x over previous
//
#include <hip/hip_runtime.h>

// GraphSAGE (2x SAGEConv mean + global_mean_pool) on MI355X.
// R18: revert R17's atomic-sink epilogues (agg2q WRITE exploded 12.5->100MB:
// 6.4M cross-XCD fp32 atomics to a 256KB pool = memory-side 16B each, no L2
// coalescing; R16's sorted-batch run-accumulating pool2 was the right
// structure). Keep R17's harmless wins: pscan inlined into bbuild, part at
// 8192 edges/block. Dataflow = R16: mgemm12 -> tqb fp8 + o128 hi-cols fp16;
// agg2q -> agg2h fp16; pool2 run-accumulates (fused gcnt); out divides.

constexpr int NN = 100000;    // nodes
constexpr int NE = 3200000;   // edges
constexpr int C1 = 128;       // IN_C == HID_C
constexpr int C2 = 64;        // OUT_C
constexpr int NG = 1024;      // graphs

constexpr int NBK = (NN + 511) >> 9;   // 196 buckets of 512 nodes
constexpr int CAP = 18176;             // padded edges per bucket (mean 16327)
constexpr int NSH = 13;                // src shards (harmless, 1-pass)

typedef unsigned int u32;
typedef unsigned short u16;
typedef unsigned char u8;
typedef _Float16 f16;
typedef f16 f16x8 __attribute__((ext_vector_type(8)));
typedef float f32x4 __attribute__((ext_vector_type(4)));

__device__ __forceinline__ float h2f(u32 bits16) {
  f16 h; u16 b = (u16)bits16;
  __builtin_memcpy(&h, &b, 2);
  return (float)h;
}
__device__ __forceinline__ u16 f2h(float f) {
  f16 h = (f16)f; u16 b;
  __builtin_memcpy(&b, &h, 2);
  return b;
}
__device__ __forceinline__ u32 packh2(float a, float b) {
  return (u32)f2h(a) | ((u32)f2h(b) << 16);
}
// pack 4 floats -> 4 fp8 e4m3 (one u32)
__device__ __forceinline__ u32 packq4(float a, float b, float c, float d) {
  int q = 0;
  q = __builtin_amdgcn_cvt_pk_fp8_f32(a, b, q, false);
  q = __builtin_amdgcn_cvt_pk_fp8_f32(c, d, q, true);
  return (u32)q;
}
// accumulate 4 fp8 (one u32) into 4 fp32
__device__ __forceinline__ void acc4(u32 g, float& a0, float& a1,
                                     float& a2, float& a3) {
  const auto p = __builtin_amdgcn_cvt_pk_f32_fp8((int)g, false);
  const auto q = __builtin_amdgcn_cvt_pk_f32_fp8((int)g, true);
  a0 += p[0]; a1 += p[1]; a2 += q[0]; a3 += q[1];
}
// 8 fp8 (uint2) -> 8 fp16 (uint4)
__device__ __forceinline__ uint4 q8toh8(uint2 g) {
  const auto p0 = __builtin_amdgcn_cvt_pk_f32_fp8((int)g.x, false);
  const auto p1 = __builtin_amdgcn_cvt_pk_f32_fp8((int)g.x, true);
  const auto p2 = __builtin_amdgcn_cvt_pk_f32_fp8((int)g.y, false);
  const auto p3 = __builtin_amdgcn_cvt_pk_f32_fp8((int)g.y, true);
  uint4 o;
  o.x = packh2(p0[0], p0[1]);
  o.y = packh2(p1[0], p1[1]);
  o.z = packh2(p2[0], p2[1]);
  o.w = packh2(p3[0], p3[1]);
  return o;
}

// ------- fused prep: x -> fp16+fp8, weights -> fp16 [N][K], gcur init -------
__global__ __launch_bounds__(256)
void sage_x2hw(const float* __restrict__ x, u16* __restrict__ xh,
               u32* __restrict__ xq,
               const float* __restrict__ W1l, const float* __restrict__ W1r,
               const float* __restrict__ W2l, const float* __restrict__ W2r,
               u16* __restrict__ wt1, u16* __restrict__ wt2,
               int* __restrict__ gcur) {
  const int id = blockIdx.x * 256 + threadIdx.x;
  constexpr int NX = NN * 32;
  if (id < NX) {
    const float4 v = ((const float4*)x)[id];
    uint2 o;
    o.x = packh2(v.x, v.y);
    o.y = packh2(v.z, v.w);
    ((uint2*)xh)[id] = o;
    xq[id] = packq4(v.x, v.y, v.z, v.w);
  } else if (id < NX + 128 * 256) {
    const int id2 = id - NX;
    const int n = id2 >> 8, k = id2 & 255;
    const float v = (k < 128) ? W1l[k * 128 + n] : W1r[(k - 128) * 128 + n];
    wt1[id2] = f2h(v);
  } else if (id < NX + 128 * 256 + 128 * 128) {
    const int id3 = id - NX - 128 * 256;
    const int n = id3 >> 7, k = id3 & 127;
    const float v = (n < 64) ? W2l[k * 64 + n] : W2r[k * 64 + (n - 64)];
    wt2[id3] = f2h(v);
  } else if (id < NX + 128 * 256 + 128 * 128 + NBK) {
    const int b = id - NX - 128 * 256 - 128 * 128;
    gcur[b] = b * CAP;
  }
}

// ------- partition edges into padded per-bucket regions of gpart -------
// 8192 edges/block, single edge read cached in registers.
__global__ __launch_bounds__(256)
void sage_part(const int* __restrict__ esrc, const int* __restrict__ edst,
               int* __restrict__ gcur, u32* __restrict__ gpart) {
  __shared__ int h[NBK], cur[NBK];
  for (int i = threadIdx.x; i < NBK; i += 256) h[i] = 0;
  __syncthreads();
  const int e0 = blockIdx.x * 8192 + threadIdx.x * 4;
  int4 dv[8], sv[8];
  bool val[8];
#pragma unroll
  for (int j = 0; j < 8; ++j) {
    const int e = e0 + j * 1024;
    val[j] = (e < NE);
    if (val[j]) {
      dv[j] = *(const int4*)(edst + e);
      sv[j] = *(const int4*)(esrc + e);
    }
  }
#pragma unroll
  for (int j = 0; j < 8; ++j) {
    if (val[j]) {
      atomicAdd(&h[dv[j].x >> 9], 1);
      atomicAdd(&h[dv[j].y >> 9], 1);
      atomicAdd(&h[dv[j].z >> 9], 1);
      atomicAdd(&h[dv[j].w >> 9], 1);
    }
  }
  __syncthreads();
  for (int i = threadIdx.x; i < NBK; i += 256)
    cur[i] = h[i] ? atomicAdd(&gcur[i], h[i]) : 0;
  __syncthreads();
#pragma unroll
  for (int j = 0; j < 8; ++j) {
    if (val[j]) {
      int bk, p;
      bk = dv[j].x >> 9; p = atomicAdd(&cur[bk], 1);
      if (p < (bk + 1) * CAP) gpart[p] = ((u32)sv[j].x << 9) | (u32)(dv[j].x & 511);
      bk = dv[j].y >> 9; p = atomicAdd(&cur[bk], 1);
      if (p < (bk + 1) * CAP) gpart[p] = ((u32)sv[j].y << 9) | (u32)(dv[j].y & 511);
      bk = dv[j].z >> 9; p = atomicAdd(&cur[bk], 1);
      if (p < (bk + 1) * CAP) gpart[p] = ((u32)sv[j].z << 9) | (u32)(dv[j].z & 511);
      bk = dv[j].w >> 9; p = atomicAdd(&cur[bk], 1);
      if (p < (bk + 1) * CAP) gpart[p] = ((u32)sv[j].w << 9) | (u32)(dv[j].w & 511);
    }
  }
}

// ------- one block per bucket: padded gpart -> compact csr + offs -------
// Inlined bucket prefix-scan (no pscan kernel), then 2D LDS histogram
// cnt2[node][shard] -> single shard-ordered scatter pass.
__global__ __launch_bounds__(512)
void sage_bbuild(const int* __restrict__ gcur, const u32* __restrict__ gpart,
                 int* __restrict__ offs, int* __restrict__ csr) {
  __shared__ int cnt2[512 * NSH];                     // 26 KB
  __shared__ int ssc[512];
  __shared__ int sh_c0, sh_cnt;
  const int b = blockIdx.x, t = threadIdx.x;
  // bucket prefix over gcur (all blocks do this concurrently)
  int cval = 0;
  if (t < NBK) {
    cval = gcur[t] - t * CAP;
    cval = (cval > CAP) ? CAP : cval;
  }
  ssc[t] = cval;
  __syncthreads();
  for (int d = 1; d < 512; d <<= 1) {
    const int a = (t >= d) ? ssc[t - d] : 0;
    __syncthreads();
    ssc[t] += a;
    __syncthreads();
  }
  if (t == b) { sh_c0 = ssc[t] - cval; sh_cnt = cval; }
  if (b == 0 && t == NBK - 1) offs[NN] = ssc[t];
  __syncthreads();
  const int c0 = sh_c0, cnt = sh_cnt;
  const u32* gp = gpart + (size_t)b * CAP;
  for (int i = t; i < 512 * NSH; i += 512) cnt2[i] = 0;
  __syncthreads();
  for (int e = t; e < cnt; e += 512) {
    const u32 pk = gp[e];
    atomicAdd(&cnt2[(pk & 511) * NSH + (pk >> 22)], 1);
  }
  __syncthreads();
  int deg = 0;
#pragma unroll
  for (int s = 0; s < NSH; ++s) deg += cnt2[t * NSH + s];
  ssc[t] = deg;
  __syncthreads();
  for (int d = 1; d < 512; d <<= 1) {
    const int a = (t >= d) ? ssc[t - d] : 0;
    __syncthreads();
    ssc[t] += a;
    __syncthreads();
  }
  const int pre = ssc[t] - deg;
  const int node = b * 512 + t;
  if (node < NN) offs[node] = c0 + pre;
  int run = c0 + pre;                                 // in-place count->cursor
#pragma unroll
  for (int s = 0; s < NSH; ++s) {
    const int c = cnt2[t * NSH + s];
    cnt2[t * NSH + s] = run;
    run += c;
  }
  __syncthreads();
  for (int e = t; e < cnt; e += 512) {
    const u32 pk = gp[e];
    const int p = atomicAdd(&cnt2[(pk & 511) * NSH + (pk >> 22)], 1);
    csr[p] = (int)(pk >> 9);
  }
}

// ------- aggregation 1: mean of xq (fp8 [NN][128]) -> fp8 out -------
// wave per node; half-wave (32 lanes x u32) covers the 128B row, halves
// interleave edges; 8 gathers in flight per lane.
__global__ __launch_bounds__(256)
void sage_agg1q(const int* __restrict__ offs, const int* __restrict__ csr,
                const u32* __restrict__ xq, u32* __restrict__ agg1) {
  const int node = blockIdx.x * 4 + (threadIdx.x >> 6);
  const int lane = threadIdx.x & 63;
  if (node >= NN) return;
  const int beg = offs[node], end = offs[node + 1];
  const int hf = lane >> 5, l = lane & 31;
  const u32* xb = xq + l;                             // row stride 32 u32
  float a0 = 0, a1 = 0, a2 = 0, a3 = 0;
  int e = beg + hf;
  for (; e + 14 < end; e += 16) {                     // 8 edges/half in flight
    const int i0 = csr[e],      i1 = csr[e + 2],  i2 = csr[e + 4],
              i3 = csr[e + 6],  i4 = csr[e + 8],  i5 = csr[e + 10],
              i6 = csr[e + 12], i7 = csr[e + 14];
    const u32 g0 = xb[(size_t)i0 * 32], g1 = xb[(size_t)i1 * 32],
              g2 = xb[(size_t)i2 * 32], g3 = xb[(size_t)i3 * 32],
              g4 = xb[(size_t)i4 * 32], g5 = xb[(size_t)i5 * 32],
              g6 = xb[(size_t)i6 * 32], g7 = xb[(size_t)i7 * 32];
    acc4(g0, a0, a1, a2, a3); acc4(g1, a0, a1, a2, a3);
    acc4(g2, a0, a1, a2, a3); acc4(g3, a0, a1, a2, a3);
    acc4(g4, a0, a1, a2, a3); acc4(g5, a0, a1, a2, a3);
    acc4(g6, a0, a1, a2, a3); acc4(g7, a0, a1, a2, a3);
  }
  for (; e < end; e += 2)
    acc4(xb[(size_t)csr[e] * 32], a0, a1, a2, a3);
  a0 += __shfl_xor(a0, 32);
  a1 += __shfl_xor(a1, 32);
  a2 += __shfl_xor(a2, 32);
  a3 += __shfl_xor(a3, 32);
  if (hf == 0) {
    const float inv = 1.0f / fmaxf((float)(end - beg), 1.0f);
    agg1[(size_t)node * 32 + l] = packq4(a0 * inv, a1 * inv, a2 * inv, a3 * inv);
  }
}

// ------- aggregation 2: mean of tq (fp8 [NN][64]) -> fp16 -------
__global__ __launch_bounds__(256)
void sage_agg2q(const int* __restrict__ offs, const int* __restrict__ csr,
                const u32* __restrict__ tq, u16* __restrict__ agg2h) {
  const int node = blockIdx.x * 4 + (threadIdx.x >> 6);
  const int lane = threadIdx.x & 63;
  if (node >= NN) return;
  const int beg = offs[node], end = offs[node + 1];
  const int grp = lane >> 4, l = lane & 15;
  const u32* tb = tq + l;                             // row stride 16 u32
  float a0 = 0, a1 = 0, a2 = 0, a3 = 0;
  int e = beg + grp;
  for (; e + 28 < end; e += 32) {                     // 8 edges/group in flight
    const int i0 = csr[e],      i1 = csr[e + 4],  i2 = csr[e + 8],
              i3 = csr[e + 12], i4 = csr[e + 16], i5 = csr[e + 20],
              i6 = csr[e + 24], i7 = csr[e + 28];
    const u32 g0 = tb[(size_t)i0 * 16], g1 = tb[(size_t)i1 * 16],
              g2 = tb[(size_t)i2 * 16], g3 = tb[(size_t)i3 * 16],
              g4 = tb[(size_t)i4 * 16], g5 = tb[(size_t)i5 * 16],
              g6 = tb[(size_t)i6 * 16], g7 = tb[(size_t)i7 * 16];
    acc4(g0, a0, a1, a2, a3); acc4(g1, a0, a1, a2, a3);
    acc4(g2, a0, a1, a2, a3); acc4(g3, a0, a1, a2, a3);
    acc4(g4, a0, a1, a2, a3); acc4(g5, a0, a1, a2, a3);
    acc4(g6, a0, a1, a2, a3); acc4(g7, a0, a1, a2, a3);
  }
  for (; e < end; e += 4)
    acc4(tb[(size_t)csr[e] * 16], a0, a1, a2, a3);
  a0 += __shfl_xor(a0, 16); a0 += __shfl_xor(a0, 32);
  a1 += __shfl_xor(a1, 16); a1 += __shfl_xor(a1, 32);
  a2 += __shfl_xor(a2, 16); a2 += __shfl_xor(a2, 32);
  a3 += __shfl_xor(a3, 16); a3 += __shfl_xor(a3, 32);
  if (lane < 16) {
    const float inv = 1.0f / fmaxf((float)(end - beg), 1.0f);
    uint2 o;
    o.x = packh2(a0 * inv, a1 * inv);
    o.y = packh2(a2 * inv, a3 * inv);
    *(uint2*)(agg2h + (size_t)node * 64 + l * 4) = o;
  }
}

// ------- fused MFMA GEMM, B-in-registers mapping (R16) -------
// Block 256 (4 waves), 64 rows. Wave w computes col-groups {2w, 2w+1} over
// ALL 64 rows; B-fragments preloaded in registers so MFMA depends only on
// LDS reads. h = relu([agg1|x]@[W1l;W1r]+b1) in As[0]. Outputs: t -> tqb
// fp8, t2 -> o128 hi-cols fp16.
__global__ __launch_bounds__(256)
void sage_mgemm12(const u32* __restrict__ A1q, const u16* __restrict__ A2,
                  const u16* __restrict__ wt1, const u16* __restrict__ wt2,
                  const float* __restrict__ bias,
                  u16* __restrict__ O, u8* __restrict__ tqb) {
  __shared__ __align__(16) u16 As[2][64][128];        // 32 KB
  const int t = threadIdx.x;
  const int r0 = blockIdx.x * 64;
  const int w = t >> 6, l = t & 63;
  const int lr = l & 15, lk = l >> 4;

  // preload GEMM1 B-fragments: c = 2w+j, kt = 0..7  (64 VGPR)
  f16x8 B1[2][8];
#pragma unroll
  for (int j = 0; j < 2; ++j)
#pragma unroll
    for (int kt = 0; kt < 8; ++kt)
      B1[j][kt] = *(const f16x8*)(wt1 + (((2 * w + j) * 16 + lr) * 256 + kt * 32 + lk * 8));

  // stage A1 (fp8 [NN][32 u32] -> f16) into As[0]
#pragma unroll
  for (int i = 0; i < 4; ++i) {
    const int id = i * 256 + t;
    const int row = id >> 4, c = id & 15;
    int gr = r0 + row; gr = (gr < NN) ? gr : NN - 1;
    const uint2 g = *(const uint2*)(A1q + (size_t)gr * 32 + c * 2);
    *(uint4*)(&As[0][row][(c ^ (row & 7)) * 8]) = q8toh8(g);
  }
  // stage A2 (xh fp16) into As[1]
#pragma unroll
  for (int i = 0; i < 4; ++i) {
    const int id = i * 256 + t;
    const int row = id >> 4, c = id & 15;
    int gr = r0 + row; gr = (gr < NN) ? gr : NN - 1;
    const uint4 v = *(const uint4*)(A2 + (size_t)gr * 128 + c * 8);
    *(uint4*)(&As[1][row][(c ^ (row & 7)) * 8]) = v;
  }
  __syncthreads();

  // GEMM1: K = 256 (buf 0: agg1 x W1l, buf 1: xh x W1r)
  f32x4 acc[4][2];
#pragma unroll
  for (int rt = 0; rt < 4; ++rt)
#pragma unroll
    for (int j = 0; j < 2; ++j) acc[rt][j] = (f32x4){0.f, 0.f, 0.f, 0.f};
#pragma unroll
  for (int rt = 0; rt < 4; ++rt) {
    const int ra = rt * 16 + lr;
#pragma unroll
    for (int kt = 0; kt < 8; ++kt) {
      const int buf = kt >> 2, kk = kt & 3;
      const f16x8 a = *(const f16x8*)(&As[buf][ra][((kk * 4 + lk) ^ (ra & 7)) * 8]);
      acc[rt][0] = __builtin_amdgcn_mfma_f32_16x16x32_f16(a, B1[0][kt], acc[rt][0], 0, 0, 0);
      acc[rt][1] = __builtin_amdgcn_mfma_f32_16x16x32_f16(a, B1[1][kt], acc[rt][1], 0, 0, 0);
    }
  }

  // preload GEMM2 B-fragments now (latency hides under h-write + barrier)
  f16x8 B2[2][4];
#pragma unroll
  for (int j = 0; j < 2; ++j)
#pragma unroll
    for (int kt = 0; kt < 4; ++kt)
      B2[j][kt] = *(const f16x8*)(wt2 + (((2 * w + j) * 16 + lr) * 128 + kt * 32 + lk * 8));

  __syncthreads();                                    // all GEMM1 LDS reads done

  // h = relu(acc + b1) -> As[0]; wave w writes cols 32w..32w+31, rows 0..63
#pragma unroll
  for (int j = 0; j < 2; ++j) {
    const int col = (2 * w + j) * 16 + lr;
    const float bv = bias[col];
    const int chb = col >> 3, within = col & 7;
#pragma unroll
    for (int rt = 0; rt < 4; ++rt)
#pragma unroll
      for (int r = 0; r < 4; ++r) {
        const int row = rt * 16 + lk * 4 + r;
        As[0][row][((chb ^ (row & 7)) << 3) + within] =
            f2h(fmaxf(acc[rt][j][r] + bv, 0.f));
      }
  }
  __syncthreads();

  // GEMM2: K = 128, A = h (As[0])
  f32x4 acc2[4][2];
#pragma unroll
  for (int rt = 0; rt < 4; ++rt)
#pragma unroll
    for (int j = 0; j < 2; ++j) acc2[rt][j] = (f32x4){0.f, 0.f, 0.f, 0.f};
#pragma unroll
  for (int rt = 0; rt < 4; ++rt) {
    const int ra = rt * 16 + lr;
#pragma unroll
    for (int kt = 0; kt < 4; ++kt) {
      const f16x8 a = *(const f16x8*)(&As[0][ra][((kt * 4 + lk) ^ (ra & 7)) * 8]);
      acc2[rt][0] = __builtin_amdgcn_mfma_f32_16x16x32_f16(a, B2[0][kt], acc2[rt][0], 0, 0, 0);
      acc2[rt][1] = __builtin_amdgcn_mfma_f32_16x16x32_f16(a, B2[1][kt], acc2[rt][1], 0, 0, 0);
    }
  }
  // outputs: col-group (2w+j) < 4 -> t (fp8), else t2 (fp16 hi-cols)
#pragma unroll
  for (int j = 0; j < 2; ++j) {
    const int col = (2 * w + j) * 16 + lr;
#pragma unroll
    for (int rt = 0; rt < 4; ++rt)
#pragma unroll
      for (int r = 0; r < 4; ++r) {
        const int row = r0 + rt * 16 + lk * 4 + r;
        if (row < NN) {
          if (col < 64) {                             // t -> fp8 byte
            const int pk = __builtin_amdgcn_cvt_pk_fp8_f32(acc2[rt][j][r], acc2[rt][j][r], 0, false);
            tqb[(size_t)row * 64 + col] = (u8)pk;
          } else {                                    // t2 -> o128 hi fp16
            O[(size_t)row * 128 + col] = f2h(acc2[rt][j][r]);
          }
        }
      }
  }
}

// ------------- pooling (fused node counting, sorted-batch runs) -------------
__global__ __launch_bounds__(256)
void sage_pool2(const u16* __restrict__ o128, const u16* __restrict__ agg2h,
                const float* __restrict__ b2, const int* __restrict__ batch,
                float* __restrict__ pool, int* __restrict__ gcnt) {
  const int t = threadIdx.x;
  const int c = t & 63, sl = t >> 6;
  const int n0 = blockIdx.x * 128;
  const float bv = b2[c];
  float acc = 0.f;
  int curg = -1, cnt = 0;
  for (int n = n0 + sl; n < n0 + 128 && n < NN; n += 4) {
    const int g = batch[n];
    const float v = h2f(o128[(size_t)n * 128 + 64 + c]) +
                    h2f(agg2h[(size_t)n * 64 + c]) + bv;
    if (g != curg) {
      if (curg >= 0) {
        atomicAdd(&pool[curg * C2 + c], acc);
        if (c == 0) atomicAdd(&gcnt[curg], cnt);
      }
      curg = g; acc = v; cnt = 1;
    } else {
      acc += v; cnt += 1;
    }
  }
  if (curg >= 0) {
    atomicAdd(&pool[curg * C2 + c], acc);
    if (c == 0) atomicAdd(&gcnt[curg], cnt);
  }
}

__global__ __launch_bounds__(256)
void sage_out(const float* __restrict__ pool, const int* __restrict__ gcnt,
              float* __restrict__ out) {
  const int i = blockIdx.x * 256 + threadIdx.x;
  if (i >= NG * C2) return;
  out[i] = pool[i] / fmaxf((float)gcnt[i >> 6], 1.0f);
}

extern "C" void kernel_launch(void* const* d_in, const int* in_sizes, int n_in,
                              void* d_out, int out_size, void* d_ws, size_t ws_size,
                              hipStream_t stream) {
  (void)in_sizes; (void)n_in; (void)out_size; (void)ws_size;
  const float* x     = (const float*)d_in[0];
  const float* W1l   = (const float*)d_in[1];
  const float* b1    = (const float*)d_in[2];
  const float* W1r   = (const float*)d_in[3];
  const float* W2l   = (const float*)d_in[4];
  const float* b2    = (const float*)d_in[5];
  const float* W2r   = (const float*)d_in[6];
  const int*   ei    = (const int*)d_in[7];   // [2, NE]: row0 = src, row1 = dst
  const int*   batch = (const int*)d_in[8];
  const int* esrc = ei;
  const int* edst = ei + NE;
  float* out = (float*)d_out;

  // ---- workspace carve-out (~92 MB) ----
  char* base = (char*)d_ws;
  size_t off = 0;
  auto take = [&](size_t bytes) -> char* {
    char* p = base + off;
    off += (bytes + 255) & ~(size_t)255;
    return p;
  };
  int* gcur     = (int*)take((size_t)NBK * 4);
  int* offs     = (int*)take((size_t)(NN + 1) * 4);
  int* csr      = (int*)take((size_t)NE * 4);
  char* bufA    = take((size_t)NN * 256);   // xh (f16 NNx128) -> o128 (hi-cols)
  char* bufB    = take((size_t)NN * 256);   // agg1 fp8 (12.8M) -> agg2h | tqb @+12.8M
  char* bufC    = take((size_t)NBK * CAP * 4 + (size_t)NN * 128);
                                            // [gpart padded 14.25M | xq 12.8M]
  float* pool   = (float*)take((size_t)NG * C2 * 4);  // \ one contiguous
  int*  gcnt    = (int*)take((size_t)NG * 4);         // / memset region
  u16*  wt1     = (u16*)take((size_t)128 * 256 * 2);
  u16*  wt2     = (u16*)take((size_t)128 * 128 * 2);

  u16*   xh    = (u16*)bufA;
  u16*   o128  = (u16*)bufA;                // mgemm12 hi-cols (xh consumed in-block)
  u32*   agg1  = (u32*)bufB;                // fp8 [NN][32 u32]
  u16*   agg2h = (u16*)bufB;                // overwrites agg1 (dead after mgemm12)
  u8*    tqb   = (u8*)(bufB + (size_t)NN * 128);  // fp8 t, behind agg2h
  u32*   gpart = (u32*)bufC;                // padded; dead after bbuild
  u32*   xq    = (u32*)(bufC + (size_t)NBK * CAP * 4);  // fp8 x; dead after agg1q

  const size_t zbytes = (size_t)((char*)gcnt + (size_t)NG * 4 - (char*)pool);
  hipMemsetAsync(pool, 0, zbytes, stream);  // pool + gcnt

  sage_x2hw<<<(NN * 32 + 128 * 256 + 128 * 128 + NBK + 255) / 256, 256, 0,
              stream>>>(x, xh, xq, W1l, W1r, W2l, W2r, wt1, wt2, gcur);

  // CSR build (part 8192 edges/block; bbuild inlines the bucket scan)
  const int PB = (NE + 8191) / 8192;        // 391 partition blocks
  sage_part<<<PB, 256, 0, stream>>>(esrc, edst, gcur, gpart);
  sage_bbuild<<<NBK, 512, 0, stream>>>(gcur, gpart, offs, csr);

  // layer 1 aggregation (fp8 out)
  sage_agg1q<<<(NN + 3) / 4, 256, 0, stream>>>(offs, csr, xq, agg1);

  // fused GEMMs (B-in-registers): t -> tqb fp8, t2 -> o128 hi-cols
  sage_mgemm12<<<(NN + 63) / 64, 256, 0, stream>>>(agg1, xh, wt1, wt2, b1,
                                                   o128, tqb);

  // layer 2 aggregation
  sage_agg2q<<<(NN + 3) / 4, 256, 0, stream>>>(offs, csr, (const u32*)tqb, agg2h);

  // global mean pool (node counting fused)
  sage_pool2<<<(NN + 127) / 128, 256, 0, stream>>>(o128, agg2h, b2, batch, pool, gcnt);
  sage_out<<<(NG * C2 + 255) / 256, 256, 0, stream>>>(pool, gcnt, out);
}